// Round 22
// baseline (115.500 us; speedup 1.0000x reference)
//
#include <hip/hip_runtime.h>

#define NB 2
#define CIN 64
#define DD 12
#define HWP 800
#define NPOS 9600   // DD*HWP
#define CT 32
#define QKSCALE 0.25506601f   // (1/sqrt(32)) * log2(e)  folded into Q pack

typedef __attribute__((ext_vector_type(8))) short short8;
typedef __attribute__((ext_vector_type(16))) float f32x16;

__device__ __forceinline__ ushort f2bf(float x){
    union { float f; unsigned u; } v; v.f = x;
    unsigned r = v.u + 0x7fffu + ((v.u >> 16) & 1u);   // RNE
    return (ushort)(r >> 16);
}

// ---------- K1: per-pixel softmax/argmax (in-LDS) + segment softmax ----------
__global__ __launch_bounds__(256) void seg_kernel(const float* __restrict__ preds,
                                                  int* __restrict__ a, float* __restrict__ wt)
{
    int b = blockIdx.x / DD, seg = blockIdx.x % DD;
    __shared__ float lpv[HWP];
    __shared__ int   la[HWP];
    __shared__ float red[256];
    int t = threadIdx.x;
    for (int i=t; i<HWP; i+=256){
        const float* p = preds + (size_t)b*DD*HWP + i;
        float mx = -INFINITY; int am = 0;
        #pragma unroll
        for (int d=0; d<DD; ++d){ float v = p[d*HWP]; if (v > mx){ mx=v; am=d; } }
        float s = 0.f;
        #pragma unroll
        for (int d=0; d<DD; ++d) s += __expf(p[d*HWP]-mx);
        lpv[i] = 1.f/s; la[i] = am;
        if (seg == 0) a[b*HWP+i] = am;
    }
    __syncthreads();
    float mx = -INFINITY;
    for (int i=t; i<HWP; i+=256) if (la[i]==seg) mx = fmaxf(mx, lpv[i]);
    red[t]=mx; __syncthreads();
    for (int s=128; s>0; s>>=1){ if (t<s) red[t]=fmaxf(red[t],red[t+s]); __syncthreads(); }
    float m = red[0]; __syncthreads();
    if (m == -INFINITY) return;           // empty segment (uniform branch)
    float sm = 0.f;
    for (int i=t; i<HWP; i+=256) if (la[i]==seg) sm += __expf(lpv[i]-m);
    red[t]=sm; __syncthreads();
    for (int s=128; s>0; s>>=1){ if (t<s) red[t]+=red[t+s]; __syncthreads(); }
    float ssum = red[0];
    for (int i=t; i<HWP; i+=256) if (la[i]==seg) wt[b*HWP+i] = __expf(lpv[i]-m)/ssum;
}

// ---------- K3: fused conv1 + BN-stats partials ----------
// 1200 blocks = 2 ch-halves x 600 pos-blocks(32 pos). Block handles 48 of the
// 96 output channels (8 groups x 6) -> 32-pos coalescing preserved.
__global__ __launch_bounds__(256) void conv1_kernel(const float* __restrict__ x,
    const int* __restrict__ a, const float* __restrict__ wt,
    const float* __restrict__ Wq1, const float* __restrict__ Wk1, const float* __restrict__ Wv,
    float* __restrict__ q1, float* __restrict__ k1, float* __restrict__ v1,
    float* __restrict__ part)
{
    __shared__ float lw[3072];                 // 48 rows x 64
    int cb = blockIdx.x / 600, blk = blockIdx.x - cb*600;
    for (int i=threadIdx.x; i<3072; i+=256){
        int gch = cb*48 + (i>>6), c = i&63;
        lw[i] = (gch<32) ? Wq1[gch*64+c] : (gch<64) ? Wk1[(gch-32)*64+c] : Wv[(gch-64)*64+c];
    }
    __syncthreads();
    int t = threadIdx.x;
    int posIdx = blk*32 + (t&31);
    int g = t>>5;                              // 8 groups of 6 channels
    int b = posIdx / NPOS, pos = posIdx % NPOS;
    int d = pos / HWP, pix = pos % HWP;
    float fac = 1.f;
    if (a[b*HWP+pix] == d) fac += wt[b*HWP+pix];
    float acc[6];
    #pragma unroll
    for (int j=0;j<6;++j) acc[j]=0.f;
    const float* xb = x + (size_t)b*CIN*NPOS + pos;
    int lBase = g*6;                           // row within lw
    for (int c=0;c<CIN;++c){
        float xv = xb[(size_t)c*NPOS];
        const float* wrow = &lw[lBase*64 + c];
        #pragma unroll
        for (int j=0;j<6;++j) acc[j] += xv * wrow[j*64];
    }
    #pragma unroll
    for (int j=0;j<6;++j){
        int ch = cb*48 + lBase + j;
        float val = acc[j];
        if (ch >= 32) val *= fac;
        acc[j] = val;
        if (ch < 32)       q1[((size_t)b*CT + ch)*NPOS + pos] = val;
        else if (ch < 64)  k1[((size_t)b*CT + (ch-32))*NPOS + pos] = val;
        else               v1[((size_t)b*CT + (ch-64))*NPOS + pos] = val;
    }
    #pragma unroll
    for (int j=0;j<6;++j){
        float s = acc[j], qs = acc[j]*acc[j];
        #pragma unroll
        for (int off=16; off; off>>=1){ s += __shfl_xor(s,off); qs += __shfl_xor(qs,off); }
        if ((t&31)==0){
            int ch = cb*48 + lBase + j;
            part[((size_t)ch*600 + blk)*2]   = s;
            part[((size_t)ch*600 + blk)*2+1] = qs;
        }
    }
}

// ---------- finalize stats: one block per channel ----------
__global__ __launch_bounds__(64) void statsfin_kernel(const float* __restrict__ part,
    float* __restrict__ mu, float* __restrict__ rs, int nblk)
{
    int ch = blockIdx.x;
    float s=0.f, q=0.f;
    for (int i=threadIdx.x; i<nblk; i+=64){
        s += part[((size_t)ch*nblk+i)*2];
        q += part[((size_t)ch*nblk+i)*2+1];
    }
    #pragma unroll
    for (int off=32; off; off>>=1){ s += __shfl_xor(s,off); q += __shfl_xor(q,off); }
    if (threadIdx.x==0){
        float m = s/19200.f;
        mu[ch]=m; rs[ch]=rsqrtf(q/19200.f - m*m + 1e-5f);
    }
}

// ---------- K5: conv2 (BN+ReLU fused on inputs) + stats ----------
// 1200 blocks = 2 streams (q2/k2) x 600 pos-blocks; block reads only its stream.
__global__ __launch_bounds__(256) void conv2_kernel(const float* __restrict__ q1, const float* __restrict__ k1,
    const float* __restrict__ Wq2, const float* __restrict__ Wk2,
    const float* __restrict__ mu1, const float* __restrict__ rs1,
    float* __restrict__ q2, float* __restrict__ k2, float* __restrict__ part)
{
    __shared__ float lw[1024];
    int cb = blockIdx.x / 600, blk = blockIdx.x - cb*600;
    for (int i=threadIdx.x; i<1024; i+=256) lw[i] = cb ? Wk2[i] : Wq2[i];
    __syncthreads();
    int t = threadIdx.x;
    int posIdx = blk*32 + (t&31);
    int g = t>>5;                              // 8 groups of 4 channels
    int b = posIdx / NPOS, pos = posIdx % NPOS;
    const float* src = cb ? k1 : q1;
    float* dst       = cb ? k2 : q2;
    int so = cb*32;
    int chBase = g*4;
    float acc[4];
    #pragma unroll
    for (int j=0;j<4;++j) acc[j]=0.f;
    for (int c=0;c<32;++c){
        float v = src[((size_t)b*CT + c)*NPOS + pos];
        float vn = fmaxf((v - mu1[so+c])*rs1[so+c], 0.f);
        const float* wrow = &lw[chBase*32 + c];
        #pragma unroll
        for (int j=0;j<4;++j) acc[j] += vn * wrow[j*32];
    }
    #pragma unroll
    for (int j=0;j<4;++j)
        dst[((size_t)b*CT + chBase + j)*NPOS + pos] = acc[j];
    #pragma unroll
    for (int j=0;j<4;++j){
        float s = acc[j], qs = acc[j]*acc[j];
        #pragma unroll
        for (int off=16; off; off>>=1){ s += __shfl_xor(s,off); qs += __shfl_xor(qs,off); }
        if ((t&31)==0){
            int ch = so + chBase + j;          // 0..31 = q2, 32..63 = k2
            part[((size_t)ch*600 + blk)*2]   = s;
            part[((size_t)ch*600 + blk)*2+1] = qs;
        }
    }
}

// ---------- pack: Q->bf16 [pos][ch]; K,V->MFMA-fragment tiles ----------
__global__ __launch_bounds__(256) void pack_kernel(const float* __restrict__ q2, const float* __restrict__ k2,
    const float* __restrict__ v1,
    const float* __restrict__ mu2, const float* __restrict__ rs2,
    const float* __restrict__ muv, const float* __restrict__ rsv,
    ushort* __restrict__ Qbf, ushort* __restrict__ KP, ushort* __restrict__ VP)
{
    if (blockIdx.x < 75){
        int idx = blockIdx.x*256 + threadIdx.x;   // 0..19199 (b*9600+pos)
        int b = idx / NPOS, pos = idx - b*NPOS;
        const float* qsrc = q2 + (size_t)b*CT*NPOS + pos;
        const float* ksrc = k2 + (size_t)b*CT*NPOS + pos;
        unsigned qw[16], kw[16];
        #pragma unroll
        for (int c2=0; c2<16; ++c2){
            int c0 = 2*c2, c1 = 2*c2+1;
            float a0 = fmaxf((qsrc[(size_t)c0*NPOS] - mu2[c0])*rs2[c0], 0.f)*QKSCALE;
            float a1 = fmaxf((qsrc[(size_t)c1*NPOS] - mu2[c1])*rs2[c1], 0.f)*QKSCALE;
            qw[c2] = (unsigned)f2bf(a0) | ((unsigned)f2bf(a1)<<16);
            float b0 = fmaxf((ksrc[(size_t)c0*NPOS] - mu2[32+c0])*rs2[32+c0], 0.f);
            float b1 = fmaxf((ksrc[(size_t)c1*NPOS] - mu2[32+c1])*rs2[32+c1], 0.f);
            kw[c2] = (unsigned)f2bf(b0) | ((unsigned)f2bf(b1)<<16);
        }
        uint4* qd = (uint4*)(Qbf + (size_t)idx*CT);
        #pragma unroll
        for (int j=0;j<4;++j)
            qd[j] = make_uint4(qw[4*j], qw[4*j+1], qw[4*j+2], qw[4*j+3]);
        int kb = pos >> 5, c = pos & 31;
        ushort* base = KP + ((size_t)(b*300 + kb))*1024;
        *(uint4*)(base + (c)*8)          = make_uint4(kw[0],kw[1],kw[2],kw[3]);    // ch0..7
        *(uint4*)(base + (c+32)*8)       = make_uint4(kw[4],kw[5],kw[6],kw[7]);    // ch8..15
        *(uint4*)(base + 512 + (c)*8)    = make_uint4(kw[8],kw[9],kw[10],kw[11]);  // ch16..23
        *(uint4*)(base + 512 + (c+32)*8) = make_uint4(kw[12],kw[13],kw[14],kw[15]);// ch24..31
    } else {
        int idx = (blockIdx.x-75)*256 + threadIdx.x;  // 0..76799: (b, ch, keygroup8)
        int b = idx / 38400;
        int r = idx - b*38400;
        int c = r / 1200;          // channel
        int g8 = r - c*1200;       // key-group of 8
        int key = g8*8;
        int kb = g8 >> 2, q8 = g8 & 3;
        int p = q8 >> 1, hh = q8 & 1;
        const float* vs = v1 + ((size_t)b*CT + c)*NPOS + key;
        float m = muv[c], rr = rsv[c];
        unsigned wds[4];
        #pragma unroll
        for (int j=0;j<4;++j){
            float a0 = fmaxf((vs[2*j]   - m)*rr, 0.f);
            float a1 = fmaxf((vs[2*j+1] - m)*rr, 0.f);
            wds[j] = (unsigned)f2bf(a0) | ((unsigned)f2bf(a1)<<16);
        }
        *(uint4*)(VP + ((size_t)(b*300 + kb))*1024 + p*512 + (c + 32*hh)*8)
            = make_uint4(wds[0],wds[1],wds[2],wds[3]);
    }
}

// ---------- K7: MFMA flash attention, 32x32 tiles, fragment-packed K/V ----------
// 900 blocks = 2b x 150 q-blocks(64 q) x 3 key-thirds(3200).
// 4 waves x 25 tiles; two q-tiles per wave per key-tile.
// No softmax shift (cancels in acc/lsum; range safe: p<=e^~30, lsum<=1e17).
// lsum via VALU tree; QK C-operand is a body-local zero -> target <=128 regs
// for the 4-waves/SIMD bucket. No launch_bounds cap (round-20 miscompile).
__global__ __launch_bounds__(256) void attn_kernel(const ushort* __restrict__ Qbf,
    const ushort* __restrict__ KP, const ushort* __restrict__ VP,
    float* __restrict__ pacc, float* __restrict__ plsum)
{
    __shared__ float mrg[3][64][34];           // cross-wave merge: 32 acc + 2 lsum
    int blk = blockIdx.x;
    int b = blk / 450;
    int u = blk - b*450;                       // 0..449
    int qb = u % 150, third = u / 150;
    int q0 = qb*64;
    int t = threadIdx.x, wv = t>>6, l = t&63;
    int c = l & 31, h = l >> 5;

    const char* QbU = (const char*)(Qbf + (size_t)b*NPOS*CT);
    const char* KPb = (const char*)KP;
    const char* VPb = (const char*)VP;

    union U { uint4 u; short8 s; };
    U qf0, qf1, qf2, qf3;
    qf0.u = *(const uint4*)(QbU + (((q0 + c)*CT + 8*h)<<1));
    qf1.u = *(const uint4*)(QbU + (((q0 + c)*CT + 16 + 8*h)<<1));
    qf2.u = *(const uint4*)(QbU + (((q0 + 32 + c)*CT + 8*h)<<1));
    qf3.u = *(const uint4*)(QbU + (((q0 + 32 + c)*CT + 16 + 8*h)<<1));

    f32x16 acc0, acc1;
    #pragma unroll
    for (int r=0;r<16;++r){ acc0[r]=0.f; acc1[r]=0.f; }
    float lsum0 = 0.f, lsum1 = 0.f;

    unsigned voff = (unsigned)(l*16);
    unsigned ko = (unsigned)(b*300 + third*100 + wv*25)*2048u;

    U nk0,nk1,nv0,nv1;
    nk0.u = *(const uint4*)(KPb + ko + voff);
    nk1.u = *(const uint4*)(KPb + ko + voff + 1024);
    nv0.u = *(const uint4*)(VPb + ko + voff);
    nv1.u = *(const uint4*)(VPb + ko + voff + 1024);

    for (int ck=0; ck<25; ++ck){
        U ka0=nk0, ka1=nk1, va0=nv0, va1=nv1;
        ko += (ck<24) ? 2048u : 0u;            // clamp: redundant last prefetch
        nk0.u = *(const uint4*)(KPb + ko + voff);
        nk1.u = *(const uint4*)(KPb + ko + voff + 1024);
        nv0.u = *(const uint4*)(VPb + ko + voff);
        nv1.u = *(const uint4*)(VPb + ko + voff + 1024);

        // ---- q-tile 0 ----
        {
            f32x16 z;
            #pragma unroll
            for (int r=0;r<16;++r) z[r]=0.f;
            f32x16 s = __builtin_amdgcn_mfma_f32_32x32x16_bf16(ka0.s, qf0.s, z, 0,0,0);
            s = __builtin_amdgcn_mfma_f32_32x32x16_bf16(ka1.s, qf1.s, s, 0,0,0);
            float p[16];
            #pragma unroll
            for (int r=0;r<16;++r) asm("v_exp_f32 %0, %1" : "=v"(p[r]) : "v"(s[r]));
            lsum0 += (((p[0]+p[1])+(p[2]+p[3])) + ((p[4]+p[5])+(p[6]+p[7])))
                   + (((p[8]+p[9])+(p[10]+p[11])) + ((p[12]+p[13])+(p[14]+p[15])));
            unsigned E0,E1,E2,E3,E4,E5,E6,E7;
            asm("v_cvt_pk_bf16_f32 %0,%1,%2" : "=v"(E0) : "v"(p[0]),  "v"(p[1]));
            asm("v_cvt_pk_bf16_f32 %0,%1,%2" : "=v"(E1) : "v"(p[2]),  "v"(p[3]));
            asm("v_cvt_pk_bf16_f32 %0,%1,%2" : "=v"(E2) : "v"(p[4]),  "v"(p[5]));
            asm("v_cvt_pk_bf16_f32 %0,%1,%2" : "=v"(E3) : "v"(p[6]),  "v"(p[7]));
            asm("v_cvt_pk_bf16_f32 %0,%1,%2" : "=v"(E4) : "v"(p[8]),  "v"(p[9]));
            asm("v_cvt_pk_bf16_f32 %0,%1,%2" : "=v"(E5) : "v"(p[10]), "v"(p[11]));
            asm("v_cvt_pk_bf16_f32 %0,%1,%2" : "=v"(E6) : "v"(p[12]), "v"(p[13]));
            asm("v_cvt_pk_bf16_f32 %0,%1,%2" : "=v"(E7) : "v"(p[14]), "v"(p[15]));
            asm("v_permlane32_swap_b32 %0, %1" : "+v"(E0), "+v"(E2));
            asm("v_permlane32_swap_b32 %0, %1" : "+v"(E1), "+v"(E3));
            asm("v_permlane32_swap_b32 %0, %1" : "+v"(E4), "+v"(E6));
            asm("v_permlane32_swap_b32 %0, %1" : "+v"(E5), "+v"(E7));
            U pf1, pf2;
            pf1.u = make_uint4(E0,E1,E2,E3);
            pf2.u = make_uint4(E4,E5,E6,E7);
            acc0 = __builtin_amdgcn_mfma_f32_32x32x16_bf16(va0.s, pf1.s, acc0, 0,0,0);
            acc0 = __builtin_amdgcn_mfma_f32_32x32x16_bf16(va1.s, pf2.s, acc0, 0,0,0);
        }
        // ---- q-tile 1 ----
        {
            f32x16 z;
            #pragma unroll
            for (int r=0;r<16;++r) z[r]=0.f;
            f32x16 s = __builtin_amdgcn_mfma_f32_32x32x16_bf16(ka0.s, qf2.s, z, 0,0,0);
            s = __builtin_amdgcn_mfma_f32_32x32x16_bf16(ka1.s, qf3.s, s, 0,0,0);
            float p[16];
            #pragma unroll
            for (int r=0;r<16;++r) asm("v_exp_f32 %0, %1" : "=v"(p[r]) : "v"(s[r]));
            lsum1 += (((p[0]+p[1])+(p[2]+p[3])) + ((p[4]+p[5])+(p[6]+p[7])))
                   + (((p[8]+p[9])+(p[10]+p[11])) + ((p[12]+p[13])+(p[14]+p[15])));
            unsigned E0,E1,E2,E3,E4,E5,E6,E7;
            asm("v_cvt_pk_bf16_f32 %0,%1,%2" : "=v"(E0) : "v"(p[0]),  "v"(p[1]));
            asm("v_cvt_pk_bf16_f32 %0,%1,%2" : "=v"(E1) : "v"(p[2]),  "v"(p[3]));
            asm("v_cvt_pk_bf16_f32 %0,%1,%2" : "=v"(E2) : "v"(p[4]),  "v"(p[5]));
            asm("v_cvt_pk_bf16_f32 %0,%1,%2" : "=v"(E3) : "v"(p[6]),  "v"(p[7]));
            asm("v_cvt_pk_bf16_f32 %0,%1,%2" : "=v"(E4) : "v"(p[8]),  "v"(p[9]));
            asm("v_cvt_pk_bf16_f32 %0,%1,%2" : "=v"(E5) : "v"(p[10]), "v"(p[11]));
            asm("v_cvt_pk_bf16_f32 %0,%1,%2" : "=v"(E6) : "v"(p[12]), "v"(p[13]));
            asm("v_cvt_pk_bf16_f32 %0,%1,%2" : "=v"(E7) : "v"(p[14]), "v"(p[15]));
            asm("v_permlane32_swap_b32 %0, %1" : "+v"(E0), "+v"(E2));
            asm("v_permlane32_swap_b32 %0, %1" : "+v"(E1), "+v"(E3));
            asm("v_permlane32_swap_b32 %0, %1" : "+v"(E4), "+v"(E6));
            asm("v_permlane32_swap_b32 %0, %1" : "+v"(E5), "+v"(E7));
            U pf1, pf2;
            pf1.u = make_uint4(E0,E1,E2,E3);
            pf2.u = make_uint4(E4,E5,E6,E7);
            acc1 = __builtin_amdgcn_mfma_f32_32x32x16_bf16(va0.s, pf1.s, acc1, 0,0,0);
            acc1 = __builtin_amdgcn_mfma_f32_32x32x16_bf16(va1.s, pf2.s, acc1, 0,0,0);
        }
    }

    // combine the two lane-halves' key subsets for each query column
    lsum0 += __shfl_xor(lsum0, 32);
    lsum1 += __shfl_xor(lsum1, 32);

    if (wv > 0){
        float* mb = &mrg[wv-1][l][0];
        #pragma unroll
        for (int r=0;r<16;++r){ mb[r] = acc0[r]; mb[16+r] = acc1[r]; }
        mb[32] = lsum0; mb[33] = lsum1;
    }
    __syncthreads();
    if (wv == 0){
        #pragma unroll
        for (int w2=0; w2<3; ++w2){
            const float* mb = &mrg[w2][l][0];
            #pragma unroll
            for (int r=0;r<16;++r){ acc0[r] += mb[r]; acc1[r] += mb[16+r]; }
            lsum0 += mb[32]; lsum1 += mb[33];
        }
        float* pa = pacc + (size_t)(b*3 + third)*CT*NPOS;
        int pos0 = q0 + c, pos1 = q0 + 32 + c;
        #pragma unroll
        for (int r=0;r<16;++r){
            int rw = (r&3) + 8*(r>>2) + 4*h;
            pa[(size_t)rw*NPOS + pos0] = acc0[r];
            pa[(size_t)rw*NPOS + pos1] = acc1[r];
        }
        if (h == 0){
            plsum[(size_t)(b*3+third)*NPOS + pos0] = lsum0;
            plsum[(size_t)(b*3+third)*NPOS + pos1] = lsum1;
        }
    }
}

// ---------- K8: out conv fused with third-merge ----------
// 1200 blocks = 2 out-ch halves x 600 pos-blocks (8 groups x 4 ch).
__global__ __launch_bounds__(256) void convo_kernel(const float* __restrict__ pacc,
    const float* __restrict__ plsum, const float* __restrict__ Wo,
    float* __restrict__ outraw, float* __restrict__ part)
{
    __shared__ float lw[1024];
    int cb = blockIdx.x / 600, blk = blockIdx.x - cb*600;
    for (int i=threadIdx.x; i<1024; i+=256) lw[i] = Wo[cb*1024 + i];
    __syncthreads();
    int t = threadIdx.x;
    int posIdx = blk*32 + (t&31);
    int g = t>>5;                      // 8 groups of 4 out-channels
    int b = posIdx / NPOS, pos = posIdx % NPOS;
    const float* pA = pacc + (size_t)(b*3)*CT*NPOS + pos;
    const float* pB = pacc + (size_t)(b*3+1)*CT*NPOS + pos;
    const float* pC = pacc + (size_t)(b*3+2)*CT*NPOS + pos;
    float inv = 1.f/(plsum[(size_t)(b*3)*NPOS + pos] + plsum[(size_t)(b*3+1)*NPOS + pos]
                   + plsum[(size_t)(b*3+2)*NPOS + pos]);
    int chBase = g*4;
    float acc[4];
    #pragma unroll
    for (int j=0;j<4;++j) acc[j]=0.f;
    for (int c=0;c<32;++c){
        float v = (pA[(size_t)c*NPOS] + pB[(size_t)c*NPOS] + pC[(size_t)c*NPOS]) * inv;
        const float* wrow = &lw[chBase*32 + c];
        #pragma unroll
        for (int j=0;j<4;++j) acc[j] += v * wrow[j*32];
    }
    #pragma unroll
    for (int j=0;j<4;++j)
        outraw[((size_t)b*64 + cb*32 + chBase + j)*NPOS + pos] = acc[j];
    #pragma unroll
    for (int j=0;j<4;++j){
        float s = acc[j], qs = acc[j]*acc[j];
        #pragma unroll
        for (int off=16; off; off>>=1){ s += __shfl_xor(s,off); qs += __shfl_xor(qs,off); }
        if ((t&31)==0){
            int ch = cb*32 + chBase + j;
            part[((size_t)ch*600 + blk)*2]   = s;
            part[((size_t)ch*600 + blk)*2+1] = qs;
        }
    }
}

// ---------- elementwise BN+ReLU, float4 (in-place safe) ----------
__global__ __launch_bounds__(256) void bn_relu_kernel(const float* __restrict__ src,
    const float* __restrict__ mu, const float* __restrict__ rs,
    float* __restrict__ dst, int C, int total4)
{
    int idx = blockIdx.x*256 + threadIdx.x;    // float4 index
    if (idx >= total4) return;
    int ch = ((idx*4) / NPOS) % C;             // NPOS % 4 == 0 -> single channel per float4
    float m = mu[ch], r = rs[ch];
    float4 v = ((const float4*)src)[idx];
    v.x = fmaxf((v.x-m)*r, 0.f);
    v.y = fmaxf((v.y-m)*r, 0.f);
    v.z = fmaxf((v.z-m)*r, 0.f);
    v.w = fmaxf((v.w-m)*r, 0.f);
    ((float4*)dst)[idx] = v;
}

extern "C" void kernel_launch(void* const* d_in, const int* in_sizes, int n_in,
                              void* d_out, int out_size, void* d_ws, size_t ws_size,
                              hipStream_t stream)
{
    const float* x     = (const float*)d_in[0];
    const float* preds = (const float*)d_in[1];
    const float* Wq1   = (const float*)d_in[2];
    const float* Wq2   = (const float*)d_in[3];
    const float* Wk1   = (const float*)d_in[4];
    const float* Wk2   = (const float*)d_in[5];
    const float* Wv    = (const float*)d_in[6];
    const float* Wo    = (const float*)d_in[7];
    float* out = (float*)d_out;

    float* w     = (float*)d_ws;
    int*   a_idx = (int*)d_ws;            // [0, 1600)
    float* wt    = w + 4096;
    float* mu1   = w + 6656;  // 96 (q1 0-31, k1 32-63, v1 64-95)
    float* rs1   = w + 6752;
    float* mu2   = w + 6848;  // 64 (q2 0-31, k2 32-63)
    float* rs2   = w + 6912;
    float* muo   = w + 6976;
    float* rso   = w + 7040;
    float* q1    = w + 8192;      // 614400 floats each
    float* k1    = w + 622592;
    float* v1    = w + 1236992;
    float* q2    = w + 1851392;
    float* k2    = w + 2465792;
    // bf16 tensors (q1 slot dead after conv2):
    ushort* Qbf  = (ushort*)(w + 8192);        // 614400 ushorts
    ushort* KP   = (ushort*)(w + 315392);      // 614400 ushorts (fragment tiles)
    ushort* VP   = (ushort*)(w + 3080192);     // 614400 ushorts -> ends 3387392
    // attention partials: 6 slabs (2b x 3 thirds) x 307200 = 1843200 floats
    // overlaying dead k1,v1,q2 slots:
    float* pacc  = w + 622592;    // ends 2465792
    float* plsum = w + 3387392;   // 6*9600 = 57600 -> ends 3444992
    // stats partials (600 entries per channel)
    float* part1 = w + 3444992;   // 96*600*2 = 115200 -> ends 3560192
    float* part2 = w + 3560192;   // 64*600*2 = 76800  -> ends 3636992
    float* parto = w + 3444992;   // overlays part1 (dead after statsfin #1)

    seg_kernel  <<<24,  256,0,stream>>>(preds, a_idx, wt);
    conv1_kernel<<<1200,256,0,stream>>>(x, a_idx, wt, Wq1, Wk1, Wv, q1, k1, v1, part1);
    statsfin_kernel<<<96, 64,0,stream>>>(part1, mu1, rs1, 600);
    conv2_kernel<<<1200,256,0,stream>>>(q1, k1, Wq2, Wk2, mu1, rs1, q2, k2, part2);
    statsfin_kernel<<<64, 64,0,stream>>>(part2, mu2, rs2, 600);
    pack_kernel <<<375, 256,0,stream>>>(q2, k2, v1, mu2, rs2, mu1+64, rs1+64, Qbf, KP, VP);
    attn_kernel <<<900, 256,0,stream>>>(Qbf, KP, VP, pacc, plsum);
    convo_kernel<<<1200,256,0,stream>>>(pacc, plsum, Wo, out, parto);
    statsfin_kernel<<<64, 64,0,stream>>>(parto, muo, rso, 600);
    bn_relu_kernel<<<1200,256,0,stream>>>(out, muo, rso, out, 64, 307200);
}

// Round 23
// 106.523 us; speedup vs baseline: 1.0843x; 1.0843x over previous
//
#include <hip/hip_runtime.h>

#define NB 2
#define CIN 64
#define DD 12
#define HWP 800
#define NPOS 9600   // DD*HWP
#define CT 32
#define QKSCALE 0.25506601f   // (1/sqrt(32)) * log2(e)  folded into Q pack
#define CSH 11.541560327f     // 8 * log2(e): P = exp2(S*log2e - CSH) = exp(S - 8)

typedef __attribute__((ext_vector_type(8))) short short8;
typedef __attribute__((ext_vector_type(16))) float f32x16;

__device__ __forceinline__ ushort f2bf(float x){
    union { float f; unsigned u; } v; v.f = x;
    unsigned r = v.u + 0x7fffu + ((v.u >> 16) & 1u);   // RNE
    return (ushort)(r >> 16);
}

// ---------- K1: per-pixel softmax/argmax (in-LDS) + segment softmax ----------
__global__ __launch_bounds__(256) void seg_kernel(const float* __restrict__ preds,
                                                  int* __restrict__ a, float* __restrict__ wt)
{
    int b = blockIdx.x / DD, seg = blockIdx.x % DD;
    __shared__ float lpv[HWP];
    __shared__ int   la[HWP];
    __shared__ float red[256];
    int t = threadIdx.x;
    for (int i=t; i<HWP; i+=256){
        const float* p = preds + (size_t)b*DD*HWP + i;
        float mx = -INFINITY; int am = 0;
        #pragma unroll
        for (int d=0; d<DD; ++d){ float v = p[d*HWP]; if (v > mx){ mx=v; am=d; } }
        float s = 0.f;
        #pragma unroll
        for (int d=0; d<DD; ++d) s += __expf(p[d*HWP]-mx);
        lpv[i] = 1.f/s; la[i] = am;
        if (seg == 0) a[b*HWP+i] = am;
    }
    __syncthreads();
    float mx = -INFINITY;
    for (int i=t; i<HWP; i+=256) if (la[i]==seg) mx = fmaxf(mx, lpv[i]);
    red[t]=mx; __syncthreads();
    for (int s=128; s>0; s>>=1){ if (t<s) red[t]=fmaxf(red[t],red[t+s]); __syncthreads(); }
    float m = red[0]; __syncthreads();
    if (m == -INFINITY) return;           // empty segment (uniform branch)
    float sm = 0.f;
    for (int i=t; i<HWP; i+=256) if (la[i]==seg) sm += __expf(lpv[i]-m);
    red[t]=sm; __syncthreads();
    for (int s=128; s>0; s>>=1){ if (t<s) red[t]+=red[t+s]; __syncthreads(); }
    float ssum = red[0];
    for (int i=t; i<HWP; i+=256) if (la[i]==seg) wt[b*HWP+i] = __expf(lpv[i]-m)/ssum;
}

// ---------- K3: fused conv1 + BN-stats partials ----------
// 1200 blocks = 2 ch-halves x 600 pos-blocks(32 pos). Block handles 48 of the
// 96 output channels (8 groups x 6) -> 32-pos coalescing preserved.
__global__ __launch_bounds__(256) void conv1_kernel(const float* __restrict__ x,
    const int* __restrict__ a, const float* __restrict__ wt,
    const float* __restrict__ Wq1, const float* __restrict__ Wk1, const float* __restrict__ Wv,
    float* __restrict__ q1, float* __restrict__ k1, float* __restrict__ v1,
    float* __restrict__ part)
{
    __shared__ float lw[3072];                 // 48 rows x 64
    int cb = blockIdx.x / 600, blk = blockIdx.x - cb*600;
    for (int i=threadIdx.x; i<3072; i+=256){
        int gch = cb*48 + (i>>6), c = i&63;
        lw[i] = (gch<32) ? Wq1[gch*64+c] : (gch<64) ? Wk1[(gch-32)*64+c] : Wv[(gch-64)*64+c];
    }
    __syncthreads();
    int t = threadIdx.x;
    int posIdx = blk*32 + (t&31);
    int g = t>>5;                              // 8 groups of 6 channels
    int b = posIdx / NPOS, pos = posIdx % NPOS;
    int d = pos / HWP, pix = pos % HWP;
    float fac = 1.f;
    if (a[b*HWP+pix] == d) fac += wt[b*HWP+pix];
    float acc[6];
    #pragma unroll
    for (int j=0;j<6;++j) acc[j]=0.f;
    const float* xb = x + (size_t)b*CIN*NPOS + pos;
    int lBase = g*6;                           // row within lw
    for (int c=0;c<CIN;++c){
        float xv = xb[(size_t)c*NPOS];
        const float* wrow = &lw[lBase*64 + c];
        #pragma unroll
        for (int j=0;j<6;++j) acc[j] += xv * wrow[j*64];
    }
    #pragma unroll
    for (int j=0;j<6;++j){
        int ch = cb*48 + lBase + j;
        float val = acc[j];
        if (ch >= 32) val *= fac;
        acc[j] = val;
        if (ch < 32)       q1[((size_t)b*CT + ch)*NPOS + pos] = val;
        else if (ch < 64)  k1[((size_t)b*CT + (ch-32))*NPOS + pos] = val;
        else               v1[((size_t)b*CT + (ch-64))*NPOS + pos] = val;
    }
    #pragma unroll
    for (int j=0;j<6;++j){
        float s = acc[j], qs = acc[j]*acc[j];
        #pragma unroll
        for (int off=16; off; off>>=1){ s += __shfl_xor(s,off); qs += __shfl_xor(qs,off); }
        if ((t&31)==0){
            int ch = cb*48 + lBase + j;
            part[((size_t)ch*600 + blk)*2]   = s;
            part[((size_t)ch*600 + blk)*2+1] = qs;
        }
    }
}

// ---------- finalize stats: one block per channel ----------
__global__ __launch_bounds__(64) void statsfin_kernel(const float* __restrict__ part,
    float* __restrict__ mu, float* __restrict__ rs, int nblk)
{
    int ch = blockIdx.x;
    float s=0.f, q=0.f;
    for (int i=threadIdx.x; i<nblk; i+=64){
        s += part[((size_t)ch*nblk+i)*2];
        q += part[((size_t)ch*nblk+i)*2+1];
    }
    #pragma unroll
    for (int off=32; off; off>>=1){ s += __shfl_xor(s,off); q += __shfl_xor(q,off); }
    if (threadIdx.x==0){
        float m = s/19200.f;
        mu[ch]=m; rs[ch]=rsqrtf(q/19200.f - m*m + 1e-5f);
    }
}

// ---------- K5: conv2 (BN+ReLU fused on inputs) + stats ----------
// 1200 blocks = 2 streams (q2/k2) x 600 pos-blocks; block reads only its stream.
__global__ __launch_bounds__(256) void conv2_kernel(const float* __restrict__ q1, const float* __restrict__ k1,
    const float* __restrict__ Wq2, const float* __restrict__ Wk2,
    const float* __restrict__ mu1, const float* __restrict__ rs1,
    float* __restrict__ q2, float* __restrict__ k2, float* __restrict__ part)
{
    __shared__ float lw[1024];
    int cb = blockIdx.x / 600, blk = blockIdx.x - cb*600;
    for (int i=threadIdx.x; i<1024; i+=256) lw[i] = cb ? Wk2[i] : Wq2[i];
    __syncthreads();
    int t = threadIdx.x;
    int posIdx = blk*32 + (t&31);
    int g = t>>5;                              // 8 groups of 4 channels
    int b = posIdx / NPOS, pos = posIdx % NPOS;
    const float* src = cb ? k1 : q1;
    float* dst       = cb ? k2 : q2;
    int so = cb*32;
    int chBase = g*4;
    float acc[4];
    #pragma unroll
    for (int j=0;j<4;++j) acc[j]=0.f;
    for (int c=0;c<32;++c){
        float v = src[((size_t)b*CT + c)*NPOS + pos];
        float vn = fmaxf((v - mu1[so+c])*rs1[so+c], 0.f);
        const float* wrow = &lw[chBase*32 + c];
        #pragma unroll
        for (int j=0;j<4;++j) acc[j] += vn * wrow[j*32];
    }
    #pragma unroll
    for (int j=0;j<4;++j)
        dst[((size_t)b*CT + chBase + j)*NPOS + pos] = acc[j];
    #pragma unroll
    for (int j=0;j<4;++j){
        float s = acc[j], qs = acc[j]*acc[j];
        #pragma unroll
        for (int off=16; off; off>>=1){ s += __shfl_xor(s,off); qs += __shfl_xor(qs,off); }
        if ((t&31)==0){
            int ch = so + chBase + j;          // 0..31 = q2, 32..63 = k2
            part[((size_t)ch*600 + blk)*2]   = s;
            part[((size_t)ch*600 + blk)*2+1] = qs;
        }
    }
}

// ---------- pack: Q->bf16 [pos][ch]; K,V->MFMA-fragment tiles ----------
__global__ __launch_bounds__(256) void pack_kernel(const float* __restrict__ q2, const float* __restrict__ k2,
    const float* __restrict__ v1,
    const float* __restrict__ mu2, const float* __restrict__ rs2,
    const float* __restrict__ muv, const float* __restrict__ rsv,
    ushort* __restrict__ Qbf, ushort* __restrict__ KP, ushort* __restrict__ VP)
{
    if (blockIdx.x < 75){
        int idx = blockIdx.x*256 + threadIdx.x;   // 0..19199 (b*9600+pos)
        int b = idx / NPOS, pos = idx - b*NPOS;
        const float* qsrc = q2 + (size_t)b*CT*NPOS + pos;
        const float* ksrc = k2 + (size_t)b*CT*NPOS + pos;
        unsigned qw[16], kw[16];
        #pragma unroll
        for (int c2=0; c2<16; ++c2){
            int c0 = 2*c2, c1 = 2*c2+1;
            float a0 = fmaxf((qsrc[(size_t)c0*NPOS] - mu2[c0])*rs2[c0], 0.f)*QKSCALE;
            float a1 = fmaxf((qsrc[(size_t)c1*NPOS] - mu2[c1])*rs2[c1], 0.f)*QKSCALE;
            qw[c2] = (unsigned)f2bf(a0) | ((unsigned)f2bf(a1)<<16);
            float b0 = fmaxf((ksrc[(size_t)c0*NPOS] - mu2[32+c0])*rs2[32+c0], 0.f);
            float b1 = fmaxf((ksrc[(size_t)c1*NPOS] - mu2[32+c1])*rs2[32+c1], 0.f);
            kw[c2] = (unsigned)f2bf(b0) | ((unsigned)f2bf(b1)<<16);
        }
        uint4* qd = (uint4*)(Qbf + (size_t)idx*CT);
        #pragma unroll
        for (int j=0;j<4;++j)
            qd[j] = make_uint4(qw[4*j], qw[4*j+1], qw[4*j+2], qw[4*j+3]);
        int kb = pos >> 5, c = pos & 31;
        ushort* base = KP + ((size_t)(b*300 + kb))*1024;
        *(uint4*)(base + (c)*8)          = make_uint4(kw[0],kw[1],kw[2],kw[3]);    // ch0..7
        *(uint4*)(base + (c+32)*8)       = make_uint4(kw[4],kw[5],kw[6],kw[7]);    // ch8..15
        *(uint4*)(base + 512 + (c)*8)    = make_uint4(kw[8],kw[9],kw[10],kw[11]);  // ch16..23
        *(uint4*)(base + 512 + (c+32)*8) = make_uint4(kw[12],kw[13],kw[14],kw[15]);// ch24..31
    } else {
        int idx = (blockIdx.x-75)*256 + threadIdx.x;  // 0..76799: (b, ch, keygroup8)
        int b = idx / 38400;
        int r = idx - b*38400;
        int c = r / 1200;          // channel
        int g8 = r - c*1200;       // key-group of 8
        int key = g8*8;
        int kb = g8 >> 2, q8 = g8 & 3;
        int p = q8 >> 1, hh = q8 & 1;
        const float* vs = v1 + ((size_t)b*CT + c)*NPOS + key;
        float m = muv[c], rr = rsv[c];
        unsigned wds[4];
        #pragma unroll
        for (int j=0;j<4;++j){
            float a0 = fmaxf((vs[2*j]   - m)*rr, 0.f);
            float a1 = fmaxf((vs[2*j+1] - m)*rr, 0.f);
            wds[j] = (unsigned)f2bf(a0) | ((unsigned)f2bf(a1)<<16);
        }
        *(uint4*)(VP + ((size_t)(b*300 + kb))*1024 + p*512 + (c + 32*hh)*8)
            = make_uint4(wds[0],wds[1],wds[2],wds[3]);
    }
}

// ---------- K7: MFMA flash attention, 32x32 tiles, fragment-packed K/V ----------
// 900 blocks = 2b x 150 q-blocks(64 q) x 3 key-thirds(3200).
// 4 waves x 25 tiles; two q-tiles per wave per key-tile (halves K/V L2 traffic);
// lsum via ones-MFMA (measured best: VALU-tree lsum +9us at same occupancy,
// reg-diet landed at 132 regs -- 4 over the 128 bucket -- so no occupancy gain).
__global__ __launch_bounds__(256) void attn_kernel(const ushort* __restrict__ Qbf,
    const ushort* __restrict__ KP, const ushort* __restrict__ VP,
    float* __restrict__ pacc, float* __restrict__ plsum)
{
    __shared__ float mrg[3][64][34];           // cross-wave merge: 32 acc + 2 lsum
    int blk = blockIdx.x;
    int b = blk / 450;
    int u = blk - b*450;                       // 0..449
    int qb = u % 150, third = u / 150;
    int q0 = qb*64;
    int t = threadIdx.x, wv = t>>6, l = t&63;
    int c = l & 31, h = l >> 5;

    const char* QbU = (const char*)(Qbf + (size_t)b*NPOS*CT);
    const char* KPb = (const char*)KP;
    const char* VPb = (const char*)VP;

    union U { uint4 u; short8 s; };
    U qf0, qf1, qf2, qf3;
    qf0.u = *(const uint4*)(QbU + (((q0 + c)*CT + 8*h)<<1));
    qf1.u = *(const uint4*)(QbU + (((q0 + c)*CT + 16 + 8*h)<<1));
    qf2.u = *(const uint4*)(QbU + (((q0 + 32 + c)*CT + 8*h)<<1));
    qf3.u = *(const uint4*)(QbU + (((q0 + 32 + c)*CT + 16 + 8*h)<<1));

    U ones; ones.u = make_uint4(0x3F803F80u,0x3F803F80u,0x3F803F80u,0x3F803F80u);

    f32x16 acc0, acc1, accl0, accl1, cinit;
    #pragma unroll
    for (int r=0;r<16;++r){ acc0[r]=0.f; acc1[r]=0.f; accl0[r]=0.f; accl1[r]=0.f; cinit[r]=-CSH; }

    unsigned voff = (unsigned)(l*16);
    unsigned ko = (unsigned)(b*300 + third*100 + wv*25)*2048u;

    U nk0,nk1,nv0,nv1;
    nk0.u = *(const uint4*)(KPb + ko + voff);
    nk1.u = *(const uint4*)(KPb + ko + voff + 1024);
    nv0.u = *(const uint4*)(VPb + ko + voff);
    nv1.u = *(const uint4*)(VPb + ko + voff + 1024);

    for (int ck=0; ck<25; ++ck){
        U ka0=nk0, ka1=nk1, va0=nv0, va1=nv1;
        ko += (ck<24) ? 2048u : 0u;            // clamp: redundant last prefetch
        nk0.u = *(const uint4*)(KPb + ko + voff);
        nk1.u = *(const uint4*)(KPb + ko + voff + 1024);
        nv0.u = *(const uint4*)(VPb + ko + voff);
        nv1.u = *(const uint4*)(VPb + ko + voff + 1024);

        // ---- q-tile 0 ----
        {
            f32x16 s = __builtin_amdgcn_mfma_f32_32x32x16_bf16(ka0.s, qf0.s, cinit,0,0,0);
            s = __builtin_amdgcn_mfma_f32_32x32x16_bf16(ka1.s, qf1.s, s, 0,0,0);
            float p[16];
            #pragma unroll
            for (int r=0;r<16;++r) asm("v_exp_f32 %0, %1" : "=v"(p[r]) : "v"(s[r]));
            unsigned E0,E1,E2,E3,E4,E5,E6,E7;
            asm("v_cvt_pk_bf16_f32 %0,%1,%2" : "=v"(E0) : "v"(p[0]),  "v"(p[1]));
            asm("v_cvt_pk_bf16_f32 %0,%1,%2" : "=v"(E1) : "v"(p[2]),  "v"(p[3]));
            asm("v_cvt_pk_bf16_f32 %0,%1,%2" : "=v"(E2) : "v"(p[4]),  "v"(p[5]));
            asm("v_cvt_pk_bf16_f32 %0,%1,%2" : "=v"(E3) : "v"(p[6]),  "v"(p[7]));
            asm("v_cvt_pk_bf16_f32 %0,%1,%2" : "=v"(E4) : "v"(p[8]),  "v"(p[9]));
            asm("v_cvt_pk_bf16_f32 %0,%1,%2" : "=v"(E5) : "v"(p[10]), "v"(p[11]));
            asm("v_cvt_pk_bf16_f32 %0,%1,%2" : "=v"(E6) : "v"(p[12]), "v"(p[13]));
            asm("v_cvt_pk_bf16_f32 %0,%1,%2" : "=v"(E7) : "v"(p[14]), "v"(p[15]));
            asm("v_permlane32_swap_b32 %0, %1" : "+v"(E0), "+v"(E2));
            asm("v_permlane32_swap_b32 %0, %1" : "+v"(E1), "+v"(E3));
            asm("v_permlane32_swap_b32 %0, %1" : "+v"(E4), "+v"(E6));
            asm("v_permlane32_swap_b32 %0, %1" : "+v"(E5), "+v"(E7));
            U pf1, pf2;
            pf1.u = make_uint4(E0,E1,E2,E3);
            pf2.u = make_uint4(E4,E5,E6,E7);
            acc0  = __builtin_amdgcn_mfma_f32_32x32x16_bf16(va0.s,  pf1.s, acc0, 0,0,0);
            accl0 = __builtin_amdgcn_mfma_f32_32x32x16_bf16(ones.s, pf1.s, accl0,0,0,0);
            acc0  = __builtin_amdgcn_mfma_f32_32x32x16_bf16(va1.s,  pf2.s, acc0, 0,0,0);
            accl0 = __builtin_amdgcn_mfma_f32_32x32x16_bf16(ones.s, pf2.s, accl0,0,0,0);
        }
        // ---- q-tile 1 ----
        {
            f32x16 s = __builtin_amdgcn_mfma_f32_32x32x16_bf16(ka0.s, qf2.s, cinit,0,0,0);
            s = __builtin_amdgcn_mfma_f32_32x32x16_bf16(ka1.s, qf3.s, s, 0,0,0);
            float p[16];
            #pragma unroll
            for (int r=0;r<16;++r) asm("v_exp_f32 %0, %1" : "=v"(p[r]) : "v"(s[r]));
            unsigned E0,E1,E2,E3,E4,E5,E6,E7;
            asm("v_cvt_pk_bf16_f32 %0,%1,%2" : "=v"(E0) : "v"(p[0]),  "v"(p[1]));
            asm("v_cvt_pk_bf16_f32 %0,%1,%2" : "=v"(E1) : "v"(p[2]),  "v"(p[3]));
            asm("v_cvt_pk_bf16_f32 %0,%1,%2" : "=v"(E2) : "v"(p[4]),  "v"(p[5]));
            asm("v_cvt_pk_bf16_f32 %0,%1,%2" : "=v"(E3) : "v"(p[6]),  "v"(p[7]));
            asm("v_cvt_pk_bf16_f32 %0,%1,%2" : "=v"(E4) : "v"(p[8]),  "v"(p[9]));
            asm("v_cvt_pk_bf16_f32 %0,%1,%2" : "=v"(E5) : "v"(p[10]), "v"(p[11]));
            asm("v_cvt_pk_bf16_f32 %0,%1,%2" : "=v"(E6) : "v"(p[12]), "v"(p[13]));
            asm("v_cvt_pk_bf16_f32 %0,%1,%2" : "=v"(E7) : "v"(p[14]), "v"(p[15]));
            asm("v_permlane32_swap_b32 %0, %1" : "+v"(E0), "+v"(E2));
            asm("v_permlane32_swap_b32 %0, %1" : "+v"(E1), "+v"(E3));
            asm("v_permlane32_swap_b32 %0, %1" : "+v"(E4), "+v"(E6));
            asm("v_permlane32_swap_b32 %0, %1" : "+v"(E5), "+v"(E7));
            U pf1, pf2;
            pf1.u = make_uint4(E0,E1,E2,E3);
            pf2.u = make_uint4(E4,E5,E6,E7);
            acc1  = __builtin_amdgcn_mfma_f32_32x32x16_bf16(va0.s,  pf1.s, acc1, 0,0,0);
            accl1 = __builtin_amdgcn_mfma_f32_32x32x16_bf16(ones.s, pf1.s, accl1,0,0,0);
            acc1  = __builtin_amdgcn_mfma_f32_32x32x16_bf16(va1.s,  pf2.s, acc1, 0,0,0);
            accl1 = __builtin_amdgcn_mfma_f32_32x32x16_bf16(ones.s, pf2.s, accl1,0,0,0);
        }
    }

    float lsum0 = accl0[0];    // every row of accl = lsum partial for query c
    float lsum1 = accl1[0];

    if (wv > 0){
        float* mb = &mrg[wv-1][l][0];
        #pragma unroll
        for (int r=0;r<16;++r){ mb[r] = acc0[r]; mb[16+r] = acc1[r]; }
        mb[32] = lsum0; mb[33] = lsum1;
    }
    __syncthreads();
    if (wv == 0){
        #pragma unroll
        for (int w2=0; w2<3; ++w2){
            const float* mb = &mrg[w2][l][0];
            #pragma unroll
            for (int r=0;r<16;++r){ acc0[r] += mb[r]; acc1[r] += mb[16+r]; }
            lsum0 += mb[32]; lsum1 += mb[33];
        }
        float* pa = pacc + (size_t)(b*3 + third)*CT*NPOS;
        int pos0 = q0 + c, pos1 = q0 + 32 + c;
        #pragma unroll
        for (int r=0;r<16;++r){
            int rw = (r&3) + 8*(r>>2) + 4*h;
            pa[(size_t)rw*NPOS + pos0] = acc0[r];
            pa[(size_t)rw*NPOS + pos1] = acc1[r];
        }
        if (h == 0){
            plsum[(size_t)(b*3+third)*NPOS + pos0] = lsum0;
            plsum[(size_t)(b*3+third)*NPOS + pos1] = lsum1;
        }
    }
}

// ---------- K8: out conv fused with third-merge ----------
// 1200 blocks = 2 out-ch halves x 600 pos-blocks (8 groups x 4 ch).
__global__ __launch_bounds__(256) void convo_kernel(const float* __restrict__ pacc,
    const float* __restrict__ plsum, const float* __restrict__ Wo,
    float* __restrict__ outraw, float* __restrict__ part)
{
    __shared__ float lw[1024];
    int cb = blockIdx.x / 600, blk = blockIdx.x - cb*600;
    for (int i=threadIdx.x; i<1024; i+=256) lw[i] = Wo[cb*1024 + i];
    __syncthreads();
    int t = threadIdx.x;
    int posIdx = blk*32 + (t&31);
    int g = t>>5;                      // 8 groups of 4 out-channels
    int b = posIdx / NPOS, pos = posIdx % NPOS;
    const float* pA = pacc + (size_t)(b*3)*CT*NPOS + pos;
    const float* pB = pacc + (size_t)(b*3+1)*CT*NPOS + pos;
    const float* pC = pacc + (size_t)(b*3+2)*CT*NPOS + pos;
    float inv = 1.f/(plsum[(size_t)(b*3)*NPOS + pos] + plsum[(size_t)(b*3+1)*NPOS + pos]
                   + plsum[(size_t)(b*3+2)*NPOS + pos]);
    int chBase = g*4;
    float acc[4];
    #pragma unroll
    for (int j=0;j<4;++j) acc[j]=0.f;
    for (int c=0;c<32;++c){
        float v = (pA[(size_t)c*NPOS] + pB[(size_t)c*NPOS] + pC[(size_t)c*NPOS]) * inv;
        const float* wrow = &lw[chBase*32 + c];
        #pragma unroll
        for (int j=0;j<4;++j) acc[j] += v * wrow[j*32];
    }
    #pragma unroll
    for (int j=0;j<4;++j)
        outraw[((size_t)b*64 + cb*32 + chBase + j)*NPOS + pos] = acc[j];
    #pragma unroll
    for (int j=0;j<4;++j){
        float s = acc[j], qs = acc[j]*acc[j];
        #pragma unroll
        for (int off=16; off; off>>=1){ s += __shfl_xor(s,off); qs += __shfl_xor(qs,off); }
        if ((t&31)==0){
            int ch = cb*32 + chBase + j;
            part[((size_t)ch*600 + blk)*2]   = s;
            part[((size_t)ch*600 + blk)*2+1] = qs;
        }
    }
}

// ---------- elementwise BN+ReLU, float4 (in-place safe) ----------
__global__ __launch_bounds__(256) void bn_relu_kernel(const float* __restrict__ src,
    const float* __restrict__ mu, const float* __restrict__ rs,
    float* __restrict__ dst, int C, int total4)
{
    int idx = blockIdx.x*256 + threadIdx.x;    // float4 index
    if (idx >= total4) return;
    int ch = ((idx*4) / NPOS) % C;             // NPOS % 4 == 0 -> single channel per float4
    float m = mu[ch], r = rs[ch];
    float4 v = ((const float4*)src)[idx];
    v.x = fmaxf((v.x-m)*r, 0.f);
    v.y = fmaxf((v.y-m)*r, 0.f);
    v.z = fmaxf((v.z-m)*r, 0.f);
    v.w = fmaxf((v.w-m)*r, 0.f);
    ((float4*)dst)[idx] = v;
}

extern "C" void kernel_launch(void* const* d_in, const int* in_sizes, int n_in,
                              void* d_out, int out_size, void* d_ws, size_t ws_size,
                              hipStream_t stream)
{
    const float* x     = (const float*)d_in[0];
    const float* preds = (const float*)d_in[1];
    const float* Wq1   = (const float*)d_in[2];
    const float* Wq2   = (const float*)d_in[3];
    const float* Wk1   = (const float*)d_in[4];
    const float* Wk2   = (const float*)d_in[5];
    const float* Wv    = (const float*)d_in[6];
    const float* Wo    = (const float*)d_in[7];
    float* out = (float*)d_out;

    float* w     = (float*)d_ws;
    int*   a_idx = (int*)d_ws;            // [0, 1600)
    float* wt    = w + 4096;
    float* mu1   = w + 6656;  // 96 (q1 0-31, k1 32-63, v1 64-95)
    float* rs1   = w + 6752;
    float* mu2   = w + 6848;  // 64 (q2 0-31, k2 32-63)
    float* rs2   = w + 6912;
    float* muo   = w + 6976;
    float* rso   = w + 7040;
    float* q1    = w + 8192;      // 614400 floats each
    float* k1    = w + 622592;
    float* v1    = w + 1236992;
    float* q2    = w + 1851392;
    float* k2    = w + 2465792;
    // bf16 tensors (q1 slot dead after conv2):
    ushort* Qbf  = (ushort*)(w + 8192);        // 614400 ushorts
    ushort* KP   = (ushort*)(w + 315392);      // 614400 ushorts (fragment tiles)
    ushort* VP   = (ushort*)(w + 3080192);     // 614400 ushorts -> ends 3387392
    // attention partials: 6 slabs (2b x 3 thirds) x 307200 = 1843200 floats
    // overlaying dead k1,v1,q2 slots:
    float* pacc  = w + 622592;    // ends 2465792
    float* plsum = w + 3387392;   // 6*9600 = 57600 -> ends 3444992
    // stats partials (600 entries per channel)
    float* part1 = w + 3444992;   // 96*600*2 = 115200 -> ends 3560192
    float* part2 = w + 3560192;   // 64*600*2 = 76800  -> ends 3636992
    float* parto = w + 3444992;   // overlays part1 (dead after statsfin #1)

    seg_kernel  <<<24,  256,0,stream>>>(preds, a_idx, wt);
    conv1_kernel<<<1200,256,0,stream>>>(x, a_idx, wt, Wq1, Wk1, Wv, q1, k1, v1, part1);
    statsfin_kernel<<<96, 64,0,stream>>>(part1, mu1, rs1, 600);
    conv2_kernel<<<1200,256,0,stream>>>(q1, k1, Wq2, Wk2, mu1, rs1, q2, k2, part2);
    statsfin_kernel<<<64, 64,0,stream>>>(part2, mu2, rs2, 600);
    pack_kernel <<<375, 256,0,stream>>>(q2, k2, v1, mu2, rs2, mu1+64, rs1+64, Qbf, KP, VP);
    attn_kernel <<<900, 256,0,stream>>>(Qbf, KP, VP, pacc, plsum);
    convo_kernel<<<1200,256,0,stream>>>(pacc, plsum, Wo, out, parto);
    statsfin_kernel<<<64, 64,0,stream>>>(parto, muo, rso, 600);
    bn_relu_kernel<<<1200,256,0,stream>>>(out, muo, rso, out, 64, 307200);
}